// Round 2
// baseline (1286.821 us; speedup 1.0000x reference)
//
#include <hip/hip_runtime.h>
#include <stdint.h>
#include <stddef.h>

typedef __bf16 bf16;
typedef __attribute__((ext_vector_type(8))) __bf16 bf16x8;
typedef __attribute__((ext_vector_type(4))) __bf16 bf16x4;
typedef __attribute__((ext_vector_type(4))) float f32x4;

#define NN 4096
#define HIDD 512
#define NE 65536

// ---------- async global->LDS, 16B per lane, wave-uniform LDS base ----------
__device__ inline void gll16(const void* g, void* l) {
    __builtin_amdgcn_global_load_lds(
        (const __attribute__((address_space(1))) void*)g,
        (__attribute__((address_space(3))) void*)l, 16, 0, 0);
}

// ---------- fp32 -> bf16 elementwise convert (n multiple of 1024) ----------
__global__ void cvt_f32_bf16(const float* __restrict__ in, bf16* __restrict__ out, int n) {
    int i = (blockIdx.x * 256 + threadIdx.x) * 4;
    if (i >= n) return;
    float4 v = *reinterpret_cast<const float4*>(in + i);
    bf16x4 o;
    o[0] = (bf16)v.x; o[1] = (bf16)v.y; o[2] = (bf16)v.z; o[3] = (bf16)v.w;
    *reinterpret_cast<bf16x4*>(out + i) = o;
}

// ---------- fp32 transpose -> bf16 with column zero-padding: out[c][r] = in[r][c] ----------
__global__ void transpose_pad_f32(const float* __restrict__ in, bf16* __restrict__ out,
                                  int R, int C, int Cpad) {
    __shared__ bf16 tile[32][33];
    int c0 = blockIdx.x * 32, r0 = blockIdx.y * 32;
    int tx = threadIdx.x, ty = threadIdx.y;
    for (int i = ty; i < 32; i += 8) {
        int r = r0 + i, c = c0 + tx;
        bf16 v = (bf16)0.f;
        if (r < R && c < C) v = (bf16)in[(size_t)r * C + c];
        tile[i][tx] = v;
    }
    __syncthreads();
    for (int i = ty; i < 32; i += 8) {
        int oc = c0 + i, orow = r0 + tx;
        if (oc < Cpad && orow < R) out[(size_t)oc * R + orow] = tile[tx][i];
    }
}

// ---------- NT GEMM: C[M,N] = A[M,K] * B[N,K]^T (+fp32 bias), m97 structure ----------
template<bool BF16_OUT, bool HAS_BIAS>
__global__ __launch_bounds__(256)
void gemm_nt(const bf16* __restrict__ A, const bf16* __restrict__ B,
             void* __restrict__ Cp, const float* __restrict__ bias,
             int M, int N, int K) {
    __shared__ __align__(16) bf16 As[128 * 32];
    __shared__ __align__(16) bf16 Bs[128 * 32];
    const int tid  = threadIdx.x;
    const int wave = tid >> 6;
    const int lane = tid & 63;
    const int m0 = blockIdx.y * 128, n0 = blockIdx.x * 128;
    const int lrow = lane >> 2;          // row within 16-row staging chunk
    const int lcol = (lane & 3) * 8;     // k element offset (8 bf16 = 16B)
    const int c0 = wave * 2;             // this wave stages chunks c0, c0+1
    const size_t arow0 = (size_t)(m0 + c0 * 16 + lrow) * K + lcol;
    const size_t arow1 = (size_t)(m0 + (c0 + 1) * 16 + lrow) * K + lcol;
    const size_t brow0 = (size_t)(n0 + c0 * 16 + lrow) * K + lcol;
    const size_t brow1 = (size_t)(n0 + (c0 + 1) * 16 + lrow) * K + lcol;
    bf16* asd0 = &As[c0 * 512];
    bf16* asd1 = &As[(c0 + 1) * 512];
    bf16* bsd0 = &Bs[c0 * 512];
    bf16* bsd1 = &Bs[(c0 + 1) * 512];

    f32x4 acc[4][4] = {};

    const int wm = (wave >> 1) * 64;
    const int wn = (wave & 1) * 64;
    const int fm = wm + (lane & 15);
    const int fn = wn + (lane & 15);
    const int fk = (lane >> 4) * 8;

    for (int k0 = 0; k0 < K; k0 += 32) {
        gll16(A + arow0 + k0, asd0);
        gll16(A + arow1 + k0, asd1);
        gll16(B + brow0 + k0, bsd0);
        gll16(B + brow1 + k0, bsd1);
        __syncthreads();
        bf16x8 af[4], bg[4];
#pragma unroll
        for (int i = 0; i < 4; ++i)
            af[i] = *reinterpret_cast<const bf16x8*>(&As[(fm + i * 16) * 32 + fk]);
#pragma unroll
        for (int j = 0; j < 4; ++j)
            bg[j] = *reinterpret_cast<const bf16x8*>(&Bs[(fn + j * 16) * 32 + fk]);
#pragma unroll
        for (int i = 0; i < 4; ++i)
#pragma unroll
            for (int j = 0; j < 4; ++j)
                acc[i][j] = __builtin_amdgcn_mfma_f32_16x16x32_bf16(af[i], bg[j], acc[i][j], 0, 0, 0);
        __syncthreads();
    }

    const int rbase = m0 + wm + (lane >> 4) * 4;
    const int cbase = n0 + wn + (lane & 15);
#pragma unroll
    for (int i = 0; i < 4; ++i) {
#pragma unroll
        for (int j = 0; j < 4; ++j) {
            int col = cbase + j * 16;
            float bv = 0.f;
            if (HAS_BIAS) bv = bias[col];
#pragma unroll
            for (int r = 0; r < 4; ++r) {
                int row = rbase + i * 16 + r;
                float v = acc[i][j][r] + bv;
                if (BF16_OUT) ((bf16*)Cp)[(size_t)row * N + col] = (bf16)v;
                else          ((float*)Cp)[(size_t)row * N + col] = v;
            }
        }
    }
}

// ---------- row L2 norm of bf16 [4096,4096], inv = 1/max(||row||,1e-12) ----------
__global__ void row_norm(const bf16* __restrict__ E, float* __restrict__ inv) {
    __shared__ float red[256];
    int r = blockIdx.x;
    float s = 0.f;
    const bf16* row = E + (size_t)r * NN;
    for (int c = threadIdx.x; c < NN; c += 256) { float v = (float)row[c]; s += v * v; }
    red[threadIdx.x] = s; __syncthreads();
    for (int off = 128; off > 0; off >>= 1) {
        if (threadIdx.x < off) red[threadIdx.x] += red[threadIdx.x + off];
        __syncthreads();
    }
    if (threadIdx.x == 0) {
        float nrm = sqrtf(red[0]);
        nrm = fmaxf(nrm, 1e-12f);
        inv[r] = 1.f / nrm;
    }
}

// in-place row scale of bf16 [4096,4096]
__global__ void scale_rows_bf16(bf16* __restrict__ E, const float* __restrict__ inv) {
    size_t idx = (size_t)blockIdx.x * 256 + threadIdx.x;
    int r = (int)(idx >> 12);
    E[idx] = (bf16)((float)E[idx] * inv[r]);
}

// ---------- CSR build ----------
__global__ void csr_count(const int* __restrict__ ei, int* __restrict__ cnt, int E) {
    int e = blockIdx.x * 256 + threadIdx.x;
    if (e < E) atomicAdd(&cnt[ei[e]], 1);
}

__global__ void scan_4096(const int* __restrict__ cnt, int* __restrict__ rs) {
    __shared__ int s[1024];
    int t = threadIdx.x;
    int b = t * 4;
    int a0 = cnt[b], a1 = cnt[b + 1], a2 = cnt[b + 2], a3 = cnt[b + 3];
    int tot = a0 + a1 + a2 + a3;
    s[t] = tot;
    __syncthreads();
    for (int off = 1; off < 1024; off <<= 1) {
        int v = (t >= off) ? s[t - off] : 0;
        __syncthreads();
        s[t] += v;
        __syncthreads();
    }
    int excl = s[t] - tot;
    rs[b] = excl; rs[b + 1] = excl + a0; rs[b + 2] = excl + a0 + a1; rs[b + 3] = excl + a0 + a1 + a2;
    if (t == 1023) rs[4096] = s[1023];
}

__global__ void csr_scatter(const int* __restrict__ ei, const float* __restrict__ ew,
                            int* __restrict__ cur, int* __restrict__ ccol,
                            float* __restrict__ cw, int E) {
    int e = blockIdx.x * 256 + threadIdx.x;
    if (e < E) {
        int r = ei[e];
        int p = atomicAdd(&cur[r], 1);
        ccol[p] = ei[E + e];
        cw[p] = ew[e];
    }
}

// ---------- one Euler diffusion step: x' = x + alpha*(Ax - x) + beta*x0 ----------
__global__ void ode_step(const float* __restrict__ xin, const float* __restrict__ x0,
                         float* __restrict__ xout, const int* __restrict__ rs,
                         const int* __restrict__ ccol, const float* __restrict__ cw,
                         const float* __restrict__ alpha_p, const float* __restrict__ beta_p) {
    int row = blockIdx.x, t = threadIdx.x;   // 128 threads, HID=512 -> float4 each
    float alpha = 1.f / (1.f + expf(-alpha_p[0]));
    float beta = beta_p[0];
    const float4* xin4 = (const float4*)xin;
    float4 acc = make_float4(0.f, 0.f, 0.f, 0.f);
    int p0 = rs[row], p1 = rs[row + 1];
    for (int p = p0; p < p1; ++p) {
        int c = ccol[p]; float w = cw[p];
        float4 v = xin4[(size_t)c * 128 + t];
        acc.x += w * v.x; acc.y += w * v.y; acc.z += w * v.z; acc.w += w * v.w;
    }
    float4 xi = xin4[(size_t)row * 128 + t];
    float4 xz = ((const float4*)x0)[(size_t)row * 128 + t];
    float4 r;
    r.x = xi.x + alpha * (acc.x - xi.x) + beta * xz.x;
    r.y = xi.y + alpha * (acc.y - xi.y) + beta * xz.y;
    r.z = xi.z + alpha * (acc.z - xi.z) + beta * xz.z;
    r.w = xi.w + alpha * (acc.w - xi.w) + beta * xz.w;
    ((float4*)xout)[(size_t)row * 128 + t] = r;
}

// ---------- epilogue 1: z = relu(nf*x8 + h); column sums + global sum/sumsq ----------
__global__ void epi1(const float* __restrict__ x8, const float* __restrict__ h,
                     const float* __restrict__ nf_p, float* __restrict__ z,
                     float* __restrict__ colsum, float* __restrict__ gst) {
    __shared__ float r1[512], r2[512];
    int b = blockIdx.x, j = threadIdx.x;   // 512 threads, 8 rows/block
    float nf = nf_p[0];
    float cp = 0.f, sq = 0.f;
    for (int i = 0; i < 8; ++i) {
        size_t idx = (size_t)(b * 8 + i) * HIDD + j;
        float v = nf * x8[idx] + h[idx];
        v = fmaxf(v, 0.f);
        z[idx] = v;
        cp += v; sq += v * v;
    }
    atomicAdd(&colsum[j], cp);
    r1[j] = cp; r2[j] = sq;
    __syncthreads();
    for (int off = 256; off > 0; off >>= 1) {
        if (j < off) { r1[j] += r1[j + off]; r2[j] += r2[j + off]; }
        __syncthreads();
    }
    if (j == 0) { atomicAdd(&gst[0], r1[0]); atomicAdd(&gst[1], r2[0]); }
}

// ---------- epilogue 2: out = (z - colmean) / global_std(ddof=1), fp32 ----------
__global__ void epi2(const float* __restrict__ z, const float* __restrict__ colsum,
                     const float* __restrict__ gst, float* __restrict__ out) {
    size_t idx = (size_t)blockIdx.x * 256 + threadIdx.x;
    int j = (int)(idx & (HIDD - 1));
    float n = (float)NN * (float)HIDD;
    float gmean = gst[0] / n;
    float var = (gst[1] - n * gmean * gmean) / (n - 1.f);
    float istd = rsqrtf(var);
    float mean = colsum[j] * (1.f / (float)NN);
    out[idx] = (z[idx] - mean) * istd;
}

extern "C" void kernel_launch(void* const* d_in, const int* in_sizes, int n_in,
                              void* d_out, int out_size, void* d_ws, size_t ws_size,
                              hipStream_t stream) {
    const float* knn  = (const float*)d_in[0];
    const float* adj  = (const float*)d_in[1];
    const float* nf   = (const float*)d_in[2];
    const float* w1   = (const float*)d_in[3];
    const float* w2   = (const float*)d_in[4];
    const float* W0   = (const float*)d_in[5];
    const float* b0   = (const float*)d_in[6];
    const float* W1   = (const float*)d_in[7];
    const float* b1   = (const float*)d_in[8];
    const float* ew   = (const float*)d_in[9];
    const float* alph = (const float*)d_in[10];
    const float* beta = (const float*)d_in[11];
    const int*   ei   = (const int*)d_in[12];

    char* w = (char*)d_ws;
    size_t off = 0;
    auto alloc = [&](size_t bytes) -> char* {
        char* p = w + off;
        off += (bytes + 255) & ~(size_t)255;
        return p;
    };
    const size_t MB32 = (size_t)NN * NN * sizeof(bf16);           // 32 MiB
    bf16* A0 = (bf16*)alloc(MB32);   // adjb -> T3
    bf16* A1 = (bf16*)alloc(MB32);   // w1t -> T2 -> embed(bf16, normalized in place)
    bf16* A2 = (bf16*)alloc(MB32);   // T1 -> w2t -> (ODE xA/xB overlay)
    bf16* knnT = (bf16*)alloc((size_t)HIDD * NN * sizeof(bf16));  // 4 MiB
    bf16* Hb   = (bf16*)alloc((size_t)NN * HIDD * sizeof(bf16));  // 4 MiB: H -> h1
    bf16* W0b  = (bf16*)alloc((size_t)HIDD * NN * sizeof(bf16));  // 4 MiB
    bf16* W1b  = (bf16*)alloc((size_t)HIDD * HIDD * sizeof(bf16));// 0.5 MiB
    float* hf  = (float*)alloc((size_t)NN * HIDD * sizeof(float));// 8 MiB
    float* inv = (float*)alloc(NN * sizeof(float));
    int*  cnt  = (int*)alloc(NN * sizeof(int));
    int*  rs   = (int*)alloc((NN + 1) * sizeof(int));
    int*  cur  = (int*)alloc(NN * sizeof(int));
    int*  ccol = (int*)alloc(NE * sizeof(int));
    float* cw  = (float*)alloc(NE * sizeof(float));
    float* colsum = (float*)alloc(HIDD * sizeof(float));
    float* gst = (float*)alloc(2 * sizeof(float));
    // ODE buffers overlay A2 (dead after T3 GEMM): 8 MiB each
    float* xA = (float*)A2;
    float* xB = (float*)(A2 + (size_t)NN * HIDD * 2);  // +16 MiB in bf16 elems -> disjoint
    (void)ws_size; (void)n_in; (void)in_sizes; (void)out_size;

    dim3 tb(32, 8);
    // adj -> bf16
    cvt_f32_bf16<<<(NN * NN) / 1024, 256, 0, stream>>>(adj, A0, NN * NN);
    // w1^T -> bf16
    transpose_pad_f32<<<dim3(128, 128), tb, 0, stream>>>(w1, A1, NN, NN, NN);
    // T1 = adj @ w1  (A=adjb, B=w1t)  -> A2
    gemm_nt<true, false><<<dim3(32, 32), 256, 0, stream>>>(A0, A1, A2, nullptr, NN, NN, NN);
    // T2 = T1 @ adj^T (B=adjb) -> A1 (w1t dead)
    gemm_nt<true, false><<<dim3(32, 32), 256, 0, stream>>>(A2, A0, A1, nullptr, NN, NN, NN);
    // w2^T -> A2's replacement... w2t -> A2 is still holding T1 (dead now) -> reuse A2? T1 dead after T2.
    transpose_pad_f32<<<dim3(128, 128), tb, 0, stream>>>(w2, A2, NN, NN, NN);
    // T3 = T2 @ w2 -> A0 (adjb dead)
    gemm_nt<true, false><<<dim3(32, 32), 256, 0, stream>>>(A1, A2, A0, nullptr, NN, NN, NN);
    // knn^T (zero-padded 500 -> 512 rows)
    transpose_pad_f32<<<dim3(16, 128), tb, 0, stream>>>(knn, knnT, NN, 500, HIDD);
    // H = T3 @ knn  [4096, 512]
    gemm_nt<true, false><<<dim3(4, 32), 256, 0, stream>>>(A0, knnT, Hb, nullptr, NN, HIDD, NN);
    // embed = H @ H^T (bf16 out) -> A1 (T2 dead)
    gemm_nt<true, false><<<dim3(32, 32), 256, 0, stream>>>(Hb, Hb, A1, nullptr, NN, NN, HIDD);
    // row-normalize in place
    row_norm<<<NN, 256, 0, stream>>>(A1, inv);
    scale_rows_bf16<<<(NN * NN) / 256, 256, 0, stream>>>(A1, inv);
    // W0, W1 -> bf16
    cvt_f32_bf16<<<(HIDD * NN) / 1024, 256, 0, stream>>>(W0, W0b, HIDD * NN);
    cvt_f32_bf16<<<(HIDD * HIDD) / 1024, 256, 0, stream>>>(W1, W1b, HIDD * HIDD);
    // h1 = embed @ W0^T + b0 -> Hb (H dead)
    gemm_nt<true, true><<<dim3(4, 32), 256, 0, stream>>>(A1, W0b, Hb, b0, NN, HIDD, NN);
    // h = h1 @ W1^T + b1 (fp32) -> hf
    gemm_nt<false, true><<<dim3(4, 32), 256, 0, stream>>>(Hb, W1b, hf, b1, NN, HIDD, HIDD);

    // CSR build
    hipMemsetAsync(cnt, 0, NN * sizeof(int), stream);
    csr_count<<<NE / 256, 256, 0, stream>>>(ei, cnt, NE);
    scan_4096<<<1, 1024, 0, stream>>>(cnt, rs);
    hipMemcpyAsync(cur, rs, NN * sizeof(int), hipMemcpyDeviceToDevice, stream);
    csr_scatter<<<NE / 256, 256, 0, stream>>>(ei, ew, cur, ccol, cw, NE);

    // 8 Euler steps: hf -> xA -> xB -> ... -> final in xB
    const float* xi = hf;
    float* xo = xA;
    for (int s = 0; s < 8; ++s) {
        ode_step<<<NN, 128, 0, stream>>>(xi, hf, xo, rs, ccol, cw, alph, beta);
        xi = xo;
        xo = (s % 2 == 0) ? xB : xA;
    }

    hipMemsetAsync(colsum, 0, HIDD * sizeof(float), stream);
    hipMemsetAsync(gst, 0, 2 * sizeof(float), stream);
    epi1<<<NN / 8, 512, 0, stream>>>(xB, hf, nf, xA, colsum, gst);
    epi2<<<(NN * HIDD) / 256, 256, 0, stream>>>(xA, colsum, gst, (float*)d_out);
}

// Round 3
// 778.040 us; speedup vs baseline: 1.6539x; 1.6539x over previous
//
#include <hip/hip_runtime.h>
#include <stdint.h>
#include <stddef.h>

typedef __bf16 bf16;
typedef __attribute__((ext_vector_type(8))) __bf16 bf16x8;
typedef __attribute__((ext_vector_type(4))) __bf16 bf16x4;
typedef __attribute__((ext_vector_type(4))) float f32x4;

#define NN 4096
#define HIDD 512
#define NE 65536

// ---------- async global->LDS, 16B per lane, wave-uniform LDS base ----------
__device__ inline void gll16(const void* g, void* l) {
    __builtin_amdgcn_global_load_lds(
        (const __attribute__((address_space(1))) void*)g,
        (__attribute__((address_space(3))) void*)l, 16, 0, 0);
}

// ---------- fp32 -> bf16 elementwise convert (n multiple of 1024) ----------
__global__ void cvt_f32_bf16(const float* __restrict__ in, bf16* __restrict__ out, int n) {
    int i = (blockIdx.x * 256 + threadIdx.x) * 4;
    if (i >= n) return;
    float4 v = *reinterpret_cast<const float4*>(in + i);
    bf16x4 o;
    o[0] = (bf16)v.x; o[1] = (bf16)v.y; o[2] = (bf16)v.z; o[3] = (bf16)v.w;
    *reinterpret_cast<bf16x4*>(out + i) = o;
}

// ---------- sum S fp32 slices of n elems -> bf16 (n multiple of 1024) ----------
__global__ void reduce_slices_bf16(const float* __restrict__ in, bf16* __restrict__ out,
                                   int n, int S) {
    int i = (blockIdx.x * 256 + threadIdx.x) * 4;
    if (i >= n) return;
    float4 s = make_float4(0.f, 0.f, 0.f, 0.f);
    for (int k = 0; k < S; ++k) {
        float4 v = *reinterpret_cast<const float4*>(in + (size_t)k * n + i);
        s.x += v.x; s.y += v.y; s.z += v.z; s.w += v.w;
    }
    bf16x4 o;
    o[0] = (bf16)s.x; o[1] = (bf16)s.y; o[2] = (bf16)s.z; o[3] = (bf16)s.w;
    *reinterpret_cast<bf16x4*>(out + i) = o;
}

// ---------- fp32 transpose -> bf16 with column zero-padding: out[c][r] = in[r][c] ----------
__global__ void transpose_pad_f32(const float* __restrict__ in, bf16* __restrict__ out,
                                  int R, int C, int Cpad) {
    __shared__ bf16 tile[32][33];
    int c0 = blockIdx.x * 32, r0 = blockIdx.y * 32;
    int tx = threadIdx.x, ty = threadIdx.y;
    for (int i = ty; i < 32; i += 8) {
        int r = r0 + i, c = c0 + tx;
        bf16 v = (bf16)0.f;
        if (r < R && c < C) v = (bf16)in[(size_t)r * C + c];
        tile[i][tx] = v;
    }
    __syncthreads();
    for (int i = ty; i < 32; i += 8) {
        int oc = c0 + i, orow = r0 + tx;
        if (oc < Cpad && orow < R) out[(size_t)oc * R + orow] = tile[tx][i];
    }
}

// ---------- bf16 transpose: out[c][r] = in[r][c], dims multiple of 32 ----------
__global__ void transpose_bf16(const bf16* __restrict__ in, bf16* __restrict__ out,
                               int R, int C) {
    __shared__ bf16 tile[32][33];
    int c0 = blockIdx.x * 32, r0 = blockIdx.y * 32;
    int tx = threadIdx.x, ty = threadIdx.y;
    for (int i = ty; i < 32; i += 8)
        tile[i][tx] = in[(size_t)(r0 + i) * C + c0 + tx];
    __syncthreads();
    for (int i = ty; i < 32; i += 8)
        out[(size_t)(c0 + i) * R + r0 + tx] = tile[tx][i];
}

// ---------- NT GEMM: C[M,N] = A[M,K] * B[N,K]^T, m97 structure ----------
// Split-K via gridDim.z: each z writes its fp32 partial at Cp + z*M*N (fp32 out only).
template<bool BF16_OUT, bool HAS_BIAS, bool ROW_SCALE>
__global__ __launch_bounds__(256)
void gemm_nt(const bf16* __restrict__ A, const bf16* __restrict__ B,
             void* __restrict__ Cp, const float* __restrict__ bias,
             const float* __restrict__ rowscale, int M, int N, int K) {
    __shared__ __align__(16) bf16 As[128 * 32];
    __shared__ __align__(16) bf16 Bs[128 * 32];
    const int tid  = threadIdx.x;
    const int wave = tid >> 6;
    const int lane = tid & 63;
    const int m0 = blockIdx.y * 128, n0 = blockIdx.x * 128;
    const int lrow = lane >> 2;
    const int lcol = (lane & 3) * 8;
    const int c0 = wave * 2;
    const size_t arow0 = (size_t)(m0 + c0 * 16 + lrow) * K + lcol;
    const size_t arow1 = (size_t)(m0 + (c0 + 1) * 16 + lrow) * K + lcol;
    const size_t brow0 = (size_t)(n0 + c0 * 16 + lrow) * K + lcol;
    const size_t brow1 = (size_t)(n0 + (c0 + 1) * 16 + lrow) * K + lcol;
    bf16* asd0 = &As[c0 * 512];
    bf16* asd1 = &As[(c0 + 1) * 512];
    bf16* bsd0 = &Bs[c0 * 512];
    bf16* bsd1 = &Bs[(c0 + 1) * 512];

    f32x4 acc[4][4] = {};

    const int wm = (wave >> 1) * 64;
    const int wn = (wave & 1) * 64;
    const int fm = wm + (lane & 15);
    const int fn = wn + (lane & 15);
    const int fk = (lane >> 4) * 8;

    const int kper = K / gridDim.z;
    const int kz0 = blockIdx.z * kper;
    const int kz1 = kz0 + kper;

    for (int k0 = kz0; k0 < kz1; k0 += 32) {
        gll16(A + arow0 + k0, asd0);
        gll16(A + arow1 + k0, asd1);
        gll16(B + brow0 + k0, bsd0);
        gll16(B + brow1 + k0, bsd1);
        __syncthreads();
        bf16x8 af[4], bg[4];
#pragma unroll
        for (int i = 0; i < 4; ++i)
            af[i] = *reinterpret_cast<const bf16x8*>(&As[(fm + i * 16) * 32 + fk]);
#pragma unroll
        for (int j = 0; j < 4; ++j)
            bg[j] = *reinterpret_cast<const bf16x8*>(&Bs[(fn + j * 16) * 32 + fk]);
#pragma unroll
        for (int i = 0; i < 4; ++i)
#pragma unroll
            for (int j = 0; j < 4; ++j)
                acc[i][j] = __builtin_amdgcn_mfma_f32_16x16x32_bf16(af[i], bg[j], acc[i][j], 0, 0, 0);
        __syncthreads();
    }

    const int rbase = m0 + wm + (lane >> 4) * 4;
    const int cbase = n0 + wn + (lane & 15);
    bf16*  outb = (bf16*)Cp;
    float* outf = (float*)Cp + (size_t)blockIdx.z * M * N;
#pragma unroll
    for (int i = 0; i < 4; ++i) {
#pragma unroll
        for (int j = 0; j < 4; ++j) {
            int col = cbase + j * 16;
            float bv = 0.f;
            if (HAS_BIAS) bv = bias[col];
#pragma unroll
            for (int r = 0; r < 4; ++r) {
                int row = rbase + i * 16 + r;
                float v = acc[i][j][r];
                if (ROW_SCALE) v *= rowscale[row];
                v += bv;
                if (BF16_OUT) outb[(size_t)row * N + col] = (bf16)v;
                else          outf[(size_t)row * N + col] = v;
            }
        }
    }
}

// ---------- column dot of Rf (fp32 [512,4096]) and Ht (bf16 [512,4096]) -> inv norm ----------
__global__ void colnorm(const bf16* __restrict__ Ht, const float* __restrict__ Rf,
                        float* __restrict__ inv) {
    int i = blockIdx.x * 256 + threadIdx.x;   // column 0..4095
    float s = 0.f;
    for (int a = 0; a < HIDD; ++a)
        s += Rf[(size_t)a * NN + i] * (float)Ht[(size_t)a * NN + i];
    inv[i] = 1.f / fmaxf(sqrtf(s), 1e-12f);
}

// ---------- CSR build ----------
__global__ void csr_count(const int* __restrict__ ei, int* __restrict__ cnt, int E) {
    int e = blockIdx.x * 256 + threadIdx.x;
    if (e < E) atomicAdd(&cnt[ei[e]], 1);
}

__global__ void scan_4096(const int* __restrict__ cnt, int* __restrict__ rs) {
    __shared__ int s[1024];
    int t = threadIdx.x;
    int b = t * 4;
    int a0 = cnt[b], a1 = cnt[b + 1], a2 = cnt[b + 2], a3 = cnt[b + 3];
    int tot = a0 + a1 + a2 + a3;
    s[t] = tot;
    __syncthreads();
    for (int off = 1; off < 1024; off <<= 1) {
        int v = (t >= off) ? s[t - off] : 0;
        __syncthreads();
        s[t] += v;
        __syncthreads();
    }
    int excl = s[t] - tot;
    rs[b] = excl; rs[b + 1] = excl + a0; rs[b + 2] = excl + a0 + a1; rs[b + 3] = excl + a0 + a1 + a2;
    if (t == 1023) rs[4096] = s[1023];
}

__global__ void csr_scatter(const int* __restrict__ ei, const float* __restrict__ ew,
                            int* __restrict__ cur, int* __restrict__ ccol,
                            float* __restrict__ cw, int E) {
    int e = blockIdx.x * 256 + threadIdx.x;
    if (e < E) {
        int r = ei[e];
        int p = atomicAdd(&cur[r], 1);
        ccol[p] = ei[E + e];
        cw[p] = ew[e];
    }
}

// ---------- one Euler diffusion step: x' = x + alpha*(Ax - x) + beta*x0 ----------
__global__ void ode_step(const float* __restrict__ xin, const float* __restrict__ x0,
                         float* __restrict__ xout, const int* __restrict__ rs,
                         const int* __restrict__ ccol, const float* __restrict__ cw,
                         const float* __restrict__ alpha_p, const float* __restrict__ beta_p) {
    int row = blockIdx.x, t = threadIdx.x;   // 128 threads, HID=512 -> float4 each
    float alpha = 1.f / (1.f + expf(-alpha_p[0]));
    float beta = beta_p[0];
    const float4* xin4 = (const float4*)xin;
    float4 acc = make_float4(0.f, 0.f, 0.f, 0.f);
    int p0 = rs[row], p1 = rs[row + 1];
    for (int p = p0; p < p1; ++p) {
        int c = ccol[p]; float w = cw[p];
        float4 v = xin4[(size_t)c * 128 + t];
        acc.x += w * v.x; acc.y += w * v.y; acc.z += w * v.z; acc.w += w * v.w;
    }
    float4 xi = xin4[(size_t)row * 128 + t];
    float4 xz = ((const float4*)x0)[(size_t)row * 128 + t];
    float4 r;
    r.x = xi.x + alpha * (acc.x - xi.x) + beta * xz.x;
    r.y = xi.y + alpha * (acc.y - xi.y) + beta * xz.y;
    r.z = xi.z + alpha * (acc.z - xi.z) + beta * xz.z;
    r.w = xi.w + alpha * (acc.w - xi.w) + beta * xz.w;
    ((float4*)xout)[(size_t)row * 128 + t] = r;
}

// ---------- epilogue 1: z = relu(nf*x8 + h); column sums + global sum/sumsq ----------
__global__ void epi1(const float* __restrict__ x8, const float* __restrict__ h,
                     const float* __restrict__ nf_p, float* __restrict__ z,
                     float* __restrict__ colsum, float* __restrict__ gst) {
    __shared__ float r1[512], r2[512];
    int b = blockIdx.x, j = threadIdx.x;   // 512 threads, 8 rows/block
    float nf = nf_p[0];
    float cp = 0.f, sq = 0.f;
    for (int i = 0; i < 8; ++i) {
        size_t idx = (size_t)(b * 8 + i) * HIDD + j;
        float v = nf * x8[idx] + h[idx];
        v = fmaxf(v, 0.f);
        z[idx] = v;
        cp += v; sq += v * v;
    }
    atomicAdd(&colsum[j], cp);
    r1[j] = cp; r2[j] = sq;
    __syncthreads();
    for (int off = 256; off > 0; off >>= 1) {
        if (j < off) { r1[j] += r1[j + off]; r2[j] += r2[j + off]; }
        __syncthreads();
    }
    if (j == 0) { atomicAdd(&gst[0], r1[0]); atomicAdd(&gst[1], r2[0]); }
}

// ---------- epilogue 2: out = (z - colmean) / global_std(ddof=1), fp32 ----------
__global__ void epi2(const float* __restrict__ z, const float* __restrict__ colsum,
                     const float* __restrict__ gst, float* __restrict__ out) {
    size_t idx = (size_t)blockIdx.x * 256 + threadIdx.x;
    int j = (int)(idx & (HIDD - 1));
    float n = (float)NN * (float)HIDD;
    float gmean = gst[0] / n;
    float var = (gst[1] - n * gmean * gmean) / (n - 1.f);
    float istd = rsqrtf(var);
    float mean = colsum[j] * (1.f / (float)NN);
    out[idx] = (z[idx] - mean) * istd;
}

extern "C" void kernel_launch(void* const* d_in, const int* in_sizes, int n_in,
                              void* d_out, int out_size, void* d_ws, size_t ws_size,
                              hipStream_t stream) {
    const float* knn  = (const float*)d_in[0];
    const float* adj  = (const float*)d_in[1];
    const float* nf   = (const float*)d_in[2];
    const float* w1   = (const float*)d_in[3];
    const float* w2   = (const float*)d_in[4];
    const float* W0   = (const float*)d_in[5];
    const float* b0   = (const float*)d_in[6];
    const float* W1   = (const float*)d_in[7];
    const float* b1   = (const float*)d_in[8];
    const float* ew   = (const float*)d_in[9];
    const float* alph = (const float*)d_in[10];
    const float* beta = (const float*)d_in[11];
    const int*   ei   = (const int*)d_in[12];

    char* w = (char*)d_ws;
    size_t off = 0;
    auto alloc = [&](size_t bytes) -> char* {
        char* p = w + off;
        off += (bytes + 255) & ~(size_t)255;
        return p;
    };
    const size_t SZ_NN  = (size_t)NN * NN * sizeof(bf16);      // 32 MiB
    const size_t SZ_TH  = (size_t)HIDD * NN * sizeof(bf16);    // 4 MiB
    bf16* Bar  = (bf16*)alloc(SZ_NN);                 // adjT -> adjb
    bf16* Car  = (bf16*)alloc(SZ_NN);                 // w2b -> w1b -> W0b -> ODE x buffers
    bf16* knnT = (bf16*)alloc(SZ_TH);
    bf16* tA   = (bf16*)alloc(SZ_TH);
    bf16* tB   = (bf16*)alloc(SZ_TH);                 // ends as H^T
    float* tf  = (float*)alloc((size_t)16 * 1024 * 1024);  // split-K partials / Rf / z
    bf16* Hm   = (bf16*)alloc(SZ_TH);                 // H [4096,512]
    bf16* Gb   = (bf16*)alloc((size_t)HIDD * HIDD * sizeof(bf16));
    bf16* M0tb = (bf16*)alloc((size_t)HIDD * HIDD * sizeof(bf16));
    bf16* h1b  = (bf16*)alloc((size_t)NN * HIDD * sizeof(bf16));
    float* hf  = (float*)alloc((size_t)NN * HIDD * sizeof(float));
    float* inv = (float*)alloc(NN * sizeof(float));
    int*  cnt  = (int*)alloc(NN * sizeof(int));
    int*  rs   = (int*)alloc((NN + 1) * sizeof(int));
    int*  cur  = (int*)alloc(NN * sizeof(int));
    int*  ccol = (int*)alloc(NE * sizeof(int));
    float* cw  = (float*)alloc(NE * sizeof(float));
    float* colsum = (float*)alloc(HIDD * sizeof(float));
    float* gst = (float*)alloc(2 * sizeof(float));
    float* xA = (float*)Car;                          // 8 MiB
    float* xB = (float*)Car + (size_t)NN * HIDD;      // next 8 MiB, inside 32 MiB arena
    (void)ws_size; (void)n_in; (void)in_sizes; (void)out_size;

    dim3 tb(32, 8);
    const int nTH = HIDD * NN;      // 2M elems
    const int nHH = HIDD * HIDD;    // 256K elems

    // ---- prep ----
    transpose_pad_f32<<<dim3(16, 128), tb, 0, stream>>>(knn, knnT, NN, 500, HIDD);
    cvt_f32_bf16<<<(NN * NN) / 1024, 256, 0, stream>>>(w2, Car, NN * NN);
    transpose_pad_f32<<<dim3(128, 128), tb, 0, stream>>>(adj, Bar, NN, NN, NN);

    // ---- chain: t1^T = knn^T w2^T ; t2^T = t1^T adj ; t3^T = t2^T w1^T ; H^T = t3^T adj^T
    // (as NT with B = {w2, adjT, w1, adj}); split-K=2, fp32 partials in tf, reduce->bf16
    gemm_nt<false, false, false><<<dim3(32, 4, 2), 256, 0, stream>>>(knnT, Car, tf, nullptr, nullptr, HIDD, NN, NN);
    reduce_slices_bf16<<<nTH / 1024, 256, 0, stream>>>(tf, tA, nTH, 2);
    gemm_nt<false, false, false><<<dim3(32, 4, 2), 256, 0, stream>>>(tA, Bar, tf, nullptr, nullptr, HIDD, NN, NN);
    reduce_slices_bf16<<<nTH / 1024, 256, 0, stream>>>(tf, tB, nTH, 2);
    cvt_f32_bf16<<<(NN * NN) / 1024, 256, 0, stream>>>(w1, Car, NN * NN);
    gemm_nt<false, false, false><<<dim3(32, 4, 2), 256, 0, stream>>>(tB, Car, tf, nullptr, nullptr, HIDD, NN, NN);
    reduce_slices_bf16<<<nTH / 1024, 256, 0, stream>>>(tf, tA, nTH, 2);
    cvt_f32_bf16<<<(NN * NN) / 1024, 256, 0, stream>>>(adj, Bar, NN * NN);
    gemm_nt<false, false, false><<<dim3(32, 4, 2), 256, 0, stream>>>(tA, Bar, tf, nullptr, nullptr, HIDD, NN, NN);
    reduce_slices_bf16<<<nTH / 1024, 256, 0, stream>>>(tf, tB, nTH, 2);   // tB = H^T

    // ---- H [4096,512] ----
    transpose_bf16<<<dim3(128, 16), tb, 0, stream>>>(tB, Hm, HIDD, NN);

    // ---- G = H^T H  [512,512], split-K=8 ----
    gemm_nt<false, false, false><<<dim3(4, 4, 8), 256, 0, stream>>>(tB, tB, tf, nullptr, nullptr, HIDD, HIDD, NN);
    reduce_slices_bf16<<<nHH / 1024, 256, 0, stream>>>(tf, Gb, nHH, 8);

    // ---- R^T = G H^T  [512,4096] fp32 (K=512) ----
    gemm_nt<false, false, false><<<dim3(32, 4, 1), 256, 0, stream>>>(Gb, Hm, tf, nullptr, nullptr, HIDD, NN, HIDD);
    // ---- norms: inv[i] = 1/max(sqrt(sum_a R^T[a,i]*H^T[a,i]), 1e-12) ----
    colnorm<<<NN / 256, 256, 0, stream>>>(tB, tf, inv);

    // ---- M0^T = W0 H  [512,512], split-K=8 ----
    cvt_f32_bf16<<<(HIDD * NN) / 1024, 256, 0, stream>>>(W0, Car, HIDD * NN);
    gemm_nt<false, false, false><<<dim3(4, 4, 8), 256, 0, stream>>>(Car, tB, tf, nullptr, nullptr, HIDD, HIDD, NN);
    reduce_slices_bf16<<<nHH / 1024, 256, 0, stream>>>(tf, M0tb, nHH, 8);

    // ---- h1 = diag(inv) H M0 + b0  [4096,512] bf16 ----
    gemm_nt<true, true, true><<<dim3(4, 32, 1), 256, 0, stream>>>(Hm, M0tb, h1b, b0, inv, NN, HIDD, HIDD);
    // ---- h = h1 W1^T + b1  [4096,512] fp32 ----
    cvt_f32_bf16<<<(HIDD * HIDD) / 1024, 256, 0, stream>>>(W1, (bf16*)((char*)Car + 16 * 1024 * 1024), HIDD * HIDD);
    bf16* W1b = (bf16*)((char*)Car + 16 * 1024 * 1024);
    gemm_nt<false, true, false><<<dim3(4, 32, 1), 256, 0, stream>>>(h1b, W1b, hf, b1, nullptr, NN, HIDD, HIDD);

    // ---- CSR build ----
    hipMemsetAsync(cnt, 0, NN * sizeof(int), stream);
    csr_count<<<NE / 256, 256, 0, stream>>>(ei, cnt, NE);
    scan_4096<<<1, 1024, 0, stream>>>(cnt, rs);
    hipMemcpyAsync(cur, rs, NN * sizeof(int), hipMemcpyDeviceToDevice, stream);
    csr_scatter<<<NE / 256, 256, 0, stream>>>(ei, ew, cur, ccol, cw, NE);

    // ---- 8 Euler steps: hf -> xA -> xB -> ... -> final in xB ----
    const float* xi = hf;
    float* xo = xA;
    for (int s = 0; s < 8; ++s) {
        ode_step<<<NN, 128, 0, stream>>>(xi, hf, xo, rs, ccol, cw, alph, beta);
        xi = xo;
        xo = (s % 2 == 0) ? xB : xA;
    }

    // ---- epilogue ----
    hipMemsetAsync(colsum, 0, HIDD * sizeof(float), stream);
    hipMemsetAsync(gst, 0, 2 * sizeof(float), stream);
    epi1<<<NN / 8, 512, 0, stream>>>(xB, hf, nf, tf, colsum, gst);
    epi2<<<(NN * HIDD) / 256, 256, 0, stream>>>(tf, colsum, gst, (float*)d_out);
}

// Round 4
// 675.477 us; speedup vs baseline: 1.9051x; 1.1518x over previous
//
#include <hip/hip_runtime.h>
#include <stdint.h>
#include <stddef.h>

typedef __bf16 bf16;
typedef __attribute__((ext_vector_type(8))) __bf16 bf16x8;
typedef __attribute__((ext_vector_type(4))) __bf16 bf16x4;
typedef __attribute__((ext_vector_type(4))) float f32x4;

#define NN 4096
#define HIDD 512
#define NE 65536

// ---------- async global->LDS, 16B per lane, wave-uniform LDS base ----------
__device__ inline void gll16(const void* g, void* l) {
    __builtin_amdgcn_global_load_lds(
        (const __attribute__((address_space(1))) void*)g,
        (__attribute__((address_space(3))) void*)l, 16, 0, 0);
}

// ---------- fp32 -> bf16 elementwise convert (n multiple of 1024) ----------
__global__ void cvt_f32_bf16(const float* __restrict__ in, bf16* __restrict__ out, int n) {
    int i = (blockIdx.x * 256 + threadIdx.x) * 4;
    if (i >= n) return;
    float4 v = *reinterpret_cast<const float4*>(in + i);
    bf16x4 o;
    o[0] = (bf16)v.x; o[1] = (bf16)v.y; o[2] = (bf16)v.z; o[3] = (bf16)v.w;
    *reinterpret_cast<bf16x4*>(out + i) = o;
}

// ---------- sum S bf16 slices of n elems -> bf16 (n multiple of 2048) ----------
__global__ void reduce_bf16_slices(const bf16* __restrict__ in, bf16* __restrict__ out,
                                   int n, int S) {
    int i = (blockIdx.x * 256 + threadIdx.x) * 8;
    if (i >= n) return;
    float acc[8] = {};
    for (int k = 0; k < S; ++k) {
        bf16x8 v = *reinterpret_cast<const bf16x8*>(in + (size_t)k * n + i);
#pragma unroll
        for (int j = 0; j < 8; ++j) acc[j] += (float)v[j];
    }
    bf16x8 o;
#pragma unroll
    for (int j = 0; j < 8; ++j) o[j] = (bf16)acc[j];
    *reinterpret_cast<bf16x8*>(out + i) = o;
}

// ---------- fp32 transpose -> bf16 with column zero-padding: out[c][r] = in[r][c] ----------
__global__ void transpose_pad_f32(const float* __restrict__ in, bf16* __restrict__ out,
                                  int R, int C, int Cpad) {
    __shared__ bf16 tile[32][33];
    int c0 = blockIdx.x * 32, r0 = blockIdx.y * 32;
    int tx = threadIdx.x, ty = threadIdx.y;
    for (int i = ty; i < 32; i += 8) {
        int r = r0 + i, c = c0 + tx;
        bf16 v = (bf16)0.f;
        if (r < R && c < C) v = (bf16)in[(size_t)r * C + c];
        tile[i][tx] = v;
    }
    __syncthreads();
    for (int i = ty; i < 32; i += 8) {
        int oc = c0 + i, orow = r0 + tx;
        if (oc < Cpad && orow < R) out[(size_t)oc * R + orow] = tile[tx][i];
    }
}

// ---------- bf16 transpose: out[c][r] = in[r][c], dims multiple of 32 ----------
__global__ void transpose_bf16(const bf16* __restrict__ in, bf16* __restrict__ out,
                               int R, int C) {
    __shared__ bf16 tile[32][33];
    int c0 = blockIdx.x * 32, r0 = blockIdx.y * 32;
    int tx = threadIdx.x, ty = threadIdx.y;
    for (int i = ty; i < 32; i += 8)
        tile[i][tx] = in[(size_t)(r0 + i) * C + c0 + tx];
    __syncthreads();
    for (int i = ty; i < 32; i += 8)
        out[(size_t)(c0 + i) * R + r0 + tx] = tile[tx][i];
}

// ---------- NT GEMM: C[M,N] = A[M,K] * B[N,K]^T, m97 structure ----------
// OMODE: 0 = fp32 out at Cp + z*M*N; 1 = bf16 out; 2 = bf16 partial at Cp + z*M*N
template<int OMODE, bool HAS_BIAS, bool ROW_SCALE>
__global__ __launch_bounds__(256)
void gemm_nt(const bf16* __restrict__ A, const bf16* __restrict__ B,
             void* __restrict__ Cp, const float* __restrict__ bias,
             const float* __restrict__ rowscale, int M, int N, int K) {
    __shared__ __align__(16) bf16 As[128 * 32];
    __shared__ __align__(16) bf16 Bs[128 * 32];
    const int tid  = threadIdx.x;
    const int wave = tid >> 6;
    const int lane = tid & 63;
    const int m0 = blockIdx.y * 128, n0 = blockIdx.x * 128;
    const int lrow = lane >> 2;
    const int lcol = (lane & 3) * 8;
    const int c0 = wave * 2;
    const size_t arow0 = (size_t)(m0 + c0 * 16 + lrow) * K + lcol;
    const size_t arow1 = (size_t)(m0 + (c0 + 1) * 16 + lrow) * K + lcol;
    const size_t brow0 = (size_t)(n0 + c0 * 16 + lrow) * K + lcol;
    const size_t brow1 = (size_t)(n0 + (c0 + 1) * 16 + lrow) * K + lcol;
    bf16* asd0 = &As[c0 * 512];
    bf16* asd1 = &As[(c0 + 1) * 512];
    bf16* bsd0 = &Bs[c0 * 512];
    bf16* bsd1 = &Bs[(c0 + 1) * 512];

    f32x4 acc[4][4] = {};

    const int wm = (wave >> 1) * 64;
    const int wn = (wave & 1) * 64;
    const int fm = wm + (lane & 15);
    const int fn = wn + (lane & 15);
    const int fk = (lane >> 4) * 8;

    const int kper = K / gridDim.z;
    const int kz0 = blockIdx.z * kper;
    const int kz1 = kz0 + kper;

    for (int k0 = kz0; k0 < kz1; k0 += 32) {
        gll16(A + arow0 + k0, asd0);
        gll16(A + arow1 + k0, asd1);
        gll16(B + brow0 + k0, bsd0);
        gll16(B + brow1 + k0, bsd1);
        __syncthreads();
        bf16x8 af[4], bg[4];
#pragma unroll
        for (int i = 0; i < 4; ++i)
            af[i] = *reinterpret_cast<const bf16x8*>(&As[(fm + i * 16) * 32 + fk]);
#pragma unroll
        for (int j = 0; j < 4; ++j)
            bg[j] = *reinterpret_cast<const bf16x8*>(&Bs[(fn + j * 16) * 32 + fk]);
#pragma unroll
        for (int i = 0; i < 4; ++i)
#pragma unroll
            for (int j = 0; j < 4; ++j)
                acc[i][j] = __builtin_amdgcn_mfma_f32_16x16x32_bf16(af[i], bg[j], acc[i][j], 0, 0, 0);
        __syncthreads();
    }

    const int rbase = m0 + wm + (lane >> 4) * 4;
    const int cbase = n0 + wn + (lane & 15);
    float* outf = (float*)Cp + (size_t)blockIdx.z * M * N;
    bf16*  outb = (bf16*)Cp;
    bf16*  outp = (bf16*)Cp + (size_t)blockIdx.z * M * N;
#pragma unroll
    for (int i = 0; i < 4; ++i) {
#pragma unroll
        for (int j = 0; j < 4; ++j) {
            int col = cbase + j * 16;
            float bv = 0.f;
            if (HAS_BIAS) bv = bias[col];
#pragma unroll
            for (int r = 0; r < 4; ++r) {
                int row = rbase + i * 16 + r;
                float v = acc[i][j][r];
                if (ROW_SCALE) v *= rowscale[row];
                v += bv;
                if (OMODE == 0)      outf[(size_t)row * N + col] = v;
                else if (OMODE == 1) outb[(size_t)row * N + col] = (bf16)v;
                else                 outp[(size_t)row * N + col] = (bf16)v;
            }
        }
    }
}

// ---------- colnorm partials: n2[i] += sum_{a in chunk} Rf[a,i]*Ht[a,i] ----------
__global__ void colnorm_part(const bf16* __restrict__ Ht, const float* __restrict__ Rf,
                             float* __restrict__ n2) {
    int i = blockIdx.x * 128 + threadIdx.x;   // 32 x-blocks cover 4096 cols
    int a0 = blockIdx.y * 64;                 // 8 y-blocks cover 512 rows
    float s = 0.f;
    for (int a = a0; a < a0 + 64; ++a)
        s += Rf[(size_t)a * NN + i] * (float)Ht[(size_t)a * NN + i];
    atomicAdd(&n2[i], s);
}

__global__ void colnorm_fin(const float* __restrict__ n2, float* __restrict__ inv) {
    int i = blockIdx.x * 256 + threadIdx.x;
    inv[i] = 1.f / fmaxf(sqrtf(n2[i]), 1e-12f);
}

// ---------- CSR build ----------
__global__ void csr_count(const int* __restrict__ ei, int* __restrict__ cnt, int E) {
    int e = blockIdx.x * 256 + threadIdx.x;
    if (e < E) atomicAdd(&cnt[ei[e]], 1);
}

__global__ void scan_4096(const int* __restrict__ cnt, int* __restrict__ rs) {
    __shared__ int s[1024];
    int t = threadIdx.x;
    int b = t * 4;
    int a0 = cnt[b], a1 = cnt[b + 1], a2 = cnt[b + 2], a3 = cnt[b + 3];
    int tot = a0 + a1 + a2 + a3;
    s[t] = tot;
    __syncthreads();
    for (int off = 1; off < 1024; off <<= 1) {
        int v = (t >= off) ? s[t - off] : 0;
        __syncthreads();
        s[t] += v;
        __syncthreads();
    }
    int excl = s[t] - tot;
    rs[b] = excl; rs[b + 1] = excl + a0; rs[b + 2] = excl + a0 + a1; rs[b + 3] = excl + a0 + a1 + a2;
    if (t == 1023) rs[4096] = s[1023];
}

__global__ void csr_scatter(const int* __restrict__ ei, const float* __restrict__ ew,
                            int* __restrict__ cur, int* __restrict__ ccol,
                            float* __restrict__ cw, int E) {
    int e = blockIdx.x * 256 + threadIdx.x;
    if (e < E) {
        int r = ei[e];
        int p = atomicAdd(&cur[r], 1);
        ccol[p] = ei[E + e];
        cw[p] = ew[e];
    }
}

// ---------- one Euler diffusion step in bf16: x' = x + alpha*(Ax - x) + beta*x0 ----------
// 1024 blocks x 256 threads; each wave (64 lanes) handles one row, 8 bf16/lane.
__global__ void ode_step_bf16(const bf16* __restrict__ xin, const bf16* __restrict__ x0,
                              bf16* __restrict__ xout, const int* __restrict__ rs,
                              const int* __restrict__ ccol, const float* __restrict__ cw,
                              const float* __restrict__ alpha_p, const float* __restrict__ beta_p) {
    int row = blockIdx.x * 4 + (threadIdx.x >> 6);
    int lane = threadIdx.x & 63;
    float alpha = 1.f / (1.f + expf(-alpha_p[0]));
    float beta = beta_p[0];
    const bf16x8* xin8 = (const bf16x8*)xin;
    float acc[8] = {};
    int p0 = rs[row], p1 = rs[row + 1];
    for (int p = p0; p < p1; ++p) {
        int c = ccol[p]; float w = cw[p];
        bf16x8 v = xin8[(size_t)c * 64 + lane];
#pragma unroll
        for (int j = 0; j < 8; ++j) acc[j] += w * (float)v[j];
    }
    bf16x8 xi = xin8[(size_t)row * 64 + lane];
    bf16x8 xz = ((const bf16x8*)x0)[(size_t)row * 64 + lane];
    bf16x8 r;
#pragma unroll
    for (int j = 0; j < 8; ++j) {
        float x = (float)xi[j];
        r[j] = (bf16)(x + alpha * (acc[j] - x) + beta * (float)xz[j]);
    }
    ((bf16x8*)xout)[(size_t)row * 64 + lane] = r;
}

// ---------- epilogue 1: z = relu(nf*x8 + h); column sums + global sum/sumsq ----------
__global__ void epi1(const bf16* __restrict__ x8, const bf16* __restrict__ h,
                     const float* __restrict__ nf_p, float* __restrict__ z,
                     float* __restrict__ colsum, float* __restrict__ gst) {
    __shared__ float r1[512], r2[512];
    int b = blockIdx.x, j = threadIdx.x;   // 512 threads, 8 rows/block
    float nf = nf_p[0];
    float cp = 0.f, sq = 0.f;
    for (int i = 0; i < 8; ++i) {
        size_t idx = (size_t)(b * 8 + i) * HIDD + j;
        float v = nf * (float)x8[idx] + (float)h[idx];
        v = fmaxf(v, 0.f);
        z[idx] = v;
        cp += v; sq += v * v;
    }
    atomicAdd(&colsum[j], cp);
    r1[j] = cp; r2[j] = sq;
    __syncthreads();
    for (int off = 256; off > 0; off >>= 1) {
        if (j < off) { r1[j] += r1[j + off]; r2[j] += r2[j + off]; }
        __syncthreads();
    }
    if (j == 0) { atomicAdd(&gst[0], r1[0]); atomicAdd(&gst[1], r2[0]); }
}

// ---------- epilogue 2: out = (z - colmean) / global_std(ddof=1), fp32 ----------
__global__ void epi2(const float* __restrict__ z, const float* __restrict__ colsum,
                     const float* __restrict__ gst, float* __restrict__ out) {
    size_t idx = (size_t)blockIdx.x * 256 + threadIdx.x;
    int j = (int)(idx & (HIDD - 1));
    float n = (float)NN * (float)HIDD;
    float gmean = gst[0] / n;
    float var = (gst[1] - n * gmean * gmean) / (n - 1.f);
    float istd = rsqrtf(var);
    float mean = colsum[j] * (1.f / (float)NN);
    out[idx] = (z[idx] - mean) * istd;
}

extern "C" void kernel_launch(void* const* d_in, const int* in_sizes, int n_in,
                              void* d_out, int out_size, void* d_ws, size_t ws_size,
                              hipStream_t stream) {
    const float* knn  = (const float*)d_in[0];
    const float* adj  = (const float*)d_in[1];
    const float* nf   = (const float*)d_in[2];
    const float* w1   = (const float*)d_in[3];
    const float* w2   = (const float*)d_in[4];
    const float* W0   = (const float*)d_in[5];
    const float* b0   = (const float*)d_in[6];
    const float* W1   = (const float*)d_in[7];
    const float* b1   = (const float*)d_in[8];
    const float* ew   = (const float*)d_in[9];
    const float* alph = (const float*)d_in[10];
    const float* beta = (const float*)d_in[11];
    const int*   ei   = (const int*)d_in[12];

    char* w = (char*)d_ws;
    size_t off = 0;
    auto alloc = [&](size_t bytes) -> char* {
        char* p = w + off;
        off += (bytes + 255) & ~(size_t)255;
        return p;
    };
    const size_t SZ_NN  = (size_t)NN * NN * sizeof(bf16);      // 32 MiB
    const size_t SZ_TH  = (size_t)HIDD * NN * sizeof(bf16);    // 4 MiB
    bf16* Bar  = (bf16*)alloc(SZ_NN);                 // adjT -> adjb
    bf16* Car  = (bf16*)alloc(SZ_NN);                 // w2b -> w1b -> W0b/W1b -> ODE x
    bf16* knnT = (bf16*)alloc(SZ_TH);
    bf16* tA   = (bf16*)alloc(SZ_TH);
    bf16* tB   = (bf16*)alloc(SZ_TH);                 // ends as H^T
    float* tf  = (float*)alloc((size_t)16 * 1024 * 1024);  // bf16 partials / Rf fp32 / z fp32
    bf16* Hm   = (bf16*)alloc(SZ_TH);                 // H [4096,512]
    bf16* Gb   = (bf16*)alloc((size_t)HIDD * HIDD * sizeof(bf16));
    bf16* M0tb = (bf16*)alloc((size_t)HIDD * HIDD * sizeof(bf16));
    bf16* h1b  = (bf16*)alloc((size_t)NN * HIDD * sizeof(bf16));
    bf16* hb   = (bf16*)alloc((size_t)NN * HIDD * sizeof(bf16));  // h in bf16
    float* inv = (float*)alloc(NN * sizeof(float));
    float* n2  = (float*)alloc(NN * sizeof(float));
    int*  cnt  = (int*)alloc(NN * sizeof(int));
    int*  rs   = (int*)alloc((NN + 1) * sizeof(int));
    int*  cur  = (int*)alloc(NN * sizeof(int));
    int*  ccol = (int*)alloc(NE * sizeof(int));
    float* cw  = (float*)alloc(NE * sizeof(float));
    float* colsum = (float*)alloc(HIDD * sizeof(float));
    float* gst = (float*)alloc(2 * sizeof(float));
    bf16* tfb = (bf16*)tf;                            // bf16 partial view of tf
    bf16* W1b = (bf16*)((char*)Car + 16 * 1024 * 1024);
    bf16* xA  = (bf16*)Car;                           // 4 MiB (W0b dead by then)
    bf16* xB  = (bf16*)Car + (size_t)NN * HIDD;       // next 4 MiB
    (void)ws_size; (void)n_in; (void)in_sizes; (void)out_size;

    dim3 tb(32, 8);
    const int nTH = HIDD * NN;      // 2M elems
    const int nHH = HIDD * HIDD;    // 256K elems

    // ---- prep ----
    transpose_pad_f32<<<dim3(16, 128), tb, 0, stream>>>(knn, knnT, NN, 500, HIDD);
    cvt_f32_bf16<<<(NN * NN) / 1024, 256, 0, stream>>>(w2, Car, NN * NN);
    transpose_pad_f32<<<dim3(128, 128), tb, 0, stream>>>(adj, Bar, NN, NN, NN);

    // ---- chain (transposed): t1^T=knn^T w2^T ; t2^T=t1^T adj ; t3^T=t2^T w1^T ; H^T=t3^T adj^T
    // NT with B = {w2, adjT, w1, adj}; split-K=4 bf16 partials in tf, deterministic reduce.
    gemm_nt<2, false, false><<<dim3(32, 4, 4), 256, 0, stream>>>(knnT, Car, tfb, nullptr, nullptr, HIDD, NN, NN);
    reduce_bf16_slices<<<nTH / 2048, 256, 0, stream>>>(tfb, tA, nTH, 4);
    gemm_nt<2, false, false><<<dim3(32, 4, 4), 256, 0, stream>>>(tA, Bar, tfb, nullptr, nullptr, HIDD, NN, NN);
    reduce_bf16_slices<<<nTH / 2048, 256, 0, stream>>>(tfb, tB, nTH, 4);
    cvt_f32_bf16<<<(NN * NN) / 1024, 256, 0, stream>>>(w1, Car, NN * NN);
    gemm_nt<2, false, false><<<dim3(32, 4, 4), 256, 0, stream>>>(tB, Car, tfb, nullptr, nullptr, HIDD, NN, NN);
    reduce_bf16_slices<<<nTH / 2048, 256, 0, stream>>>(tfb, tA, nTH, 4);
    cvt_f32_bf16<<<(NN * NN) / 1024, 256, 0, stream>>>(adj, Bar, NN * NN);
    gemm_nt<2, false, false><<<dim3(32, 4, 4), 256, 0, stream>>>(tA, Bar, tfb, nullptr, nullptr, HIDD, NN, NN);
    reduce_bf16_slices<<<nTH / 2048, 256, 0, stream>>>(tfb, tB, nTH, 4);   // tB = H^T

    // ---- H [4096,512] ----
    transpose_bf16<<<dim3(128, 16), tb, 0, stream>>>(tB, Hm, HIDD, NN);

    // ---- G = H^T H  [512,512], split-K=16 ----
    gemm_nt<2, false, false><<<dim3(4, 4, 16), 256, 0, stream>>>(tB, tB, tfb, nullptr, nullptr, HIDD, HIDD, NN);
    reduce_bf16_slices<<<nHH / 2048, 256, 0, stream>>>(tfb, Gb, nHH, 16);

    // ---- R^T = G H^T  [512,4096] fp32 (K=512) ----
    gemm_nt<0, false, false><<<dim3(32, 4, 1), 256, 0, stream>>>(Gb, Hm, tf, nullptr, nullptr, HIDD, NN, HIDD);
    // ---- norms: inv[i] = 1/max(sqrt(sum_a R^T[a,i]*H^T[a,i]), 1e-12) ----
    hipMemsetAsync(n2, 0, NN * sizeof(float), stream);
    colnorm_part<<<dim3(32, 8), 128, 0, stream>>>(tB, tf, n2);
    colnorm_fin<<<NN / 256, 256, 0, stream>>>(n2, inv);

    // ---- M0^T = W0 H  [512,512], split-K=16 ----
    cvt_f32_bf16<<<(HIDD * NN) / 1024, 256, 0, stream>>>(W0, Car, HIDD * NN);
    gemm_nt<2, false, false><<<dim3(4, 4, 16), 256, 0, stream>>>(Car, tB, tfb, nullptr, nullptr, HIDD, HIDD, NN);
    reduce_bf16_slices<<<nHH / 2048, 256, 0, stream>>>(tfb, M0tb, nHH, 16);

    // ---- h1 = diag(inv) H M0 + b0  [4096,512] bf16 ----
    gemm_nt<1, true, true><<<dim3(4, 32, 1), 256, 0, stream>>>(Hm, M0tb, h1b, b0, inv, NN, HIDD, HIDD);
    // ---- h = h1 W1^T + b1  [4096,512] bf16 ----
    cvt_f32_bf16<<<(HIDD * HIDD) / 1024, 256, 0, stream>>>(W1, W1b, HIDD * HIDD);
    gemm_nt<1, true, false><<<dim3(4, 32, 1), 256, 0, stream>>>(h1b, W1b, hb, b1, nullptr, NN, HIDD, HIDD);

    // ---- CSR build ----
    hipMemsetAsync(cnt, 0, NN * sizeof(int), stream);
    csr_count<<<NE / 256, 256, 0, stream>>>(ei, cnt, NE);
    scan_4096<<<1, 1024, 0, stream>>>(cnt, rs);
    hipMemcpyAsync(cur, rs, NN * sizeof(int), hipMemcpyDeviceToDevice, stream);
    csr_scatter<<<NE / 256, 256, 0, stream>>>(ei, ew, cur, ccol, cw, NE);

    // ---- 8 Euler steps (bf16 state): hb -> xA -> xB -> ... -> final in xB ----
    const bf16* xi = hb;
    bf16* xo = xA;
    for (int s = 0; s < 8; ++s) {
        ode_step_bf16<<<NN / 4, 256, 0, stream>>>(xi, hb, xo, rs, ccol, cw, alph, beta);
        xi = xo;
        xo = (s % 2 == 0) ? xB : xA;
    }

    // ---- epilogue ----
    hipMemsetAsync(colsum, 0, HIDD * sizeof(float), stream);
    hipMemsetAsync(gst, 0, 2 * sizeof(float), stream);
    epi1<<<NN / 8, 512, 0, stream>>>(xB, hb, nf, tf, colsum, gst);
    epi2<<<(NN * HIDD) / 256, 256, 0, stream>>>(tf, colsum, gst, (float*)d_out);
}